// Round 16
// baseline (420.249 us; speedup 1.0000x reference)
//
#include <hip/hip_runtime.h>

// Slot attention, MI355X. B=64,N=4096,S=8,D=256,H=512,ITERS=3.
// K,V never materialized (Wqk = scale*Wq^T@Wk, M = W_ih@Wv folded).
// attn: 64-row chunks (4096 blocks) so each block's chunk stays L2-resident
// between the QK read and the PV re-read; warp-private PV staging; setprio.
#define BB 64
#define NN 4096
#define SS 8
#define DD 256
#define HH 512
#define NCH 64
#define CHK 64
#define LSP3 68   // padded row stride (f32) for logits LDS

typedef __attribute__((ext_vector_type(4))) float f32x4;
typedef __attribute__((ext_vector_type(8))) short short8;
typedef __attribute__((ext_vector_type(8))) __bf16 bf16x8;

static __device__ __forceinline__ f32x4 MFMA(short8 a, short8 b, f32x4 c){
  return __builtin_amdgcn_mfma_f32_16x16x32_bf16(
      __builtin_bit_cast(bf16x8, a), __builtin_bit_cast(bf16x8, b), c, 0, 0, 0);
}

static __device__ __forceinline__ unsigned short f2bf(float f){
  unsigned int x = __builtin_bit_cast(unsigned int, f);
  x += 0x7FFFu + ((x >> 16) & 1u);
  return (unsigned short)(x >> 16);
}

static __device__ __forceinline__ unsigned int pk2(float a, float b){
  return (unsigned int)f2bf(a) | ((unsigned int)f2bf(b) << 16);
}

// ---- merged precompute:
//   blk <  256: wqkT[d2][d1] = scale * sum_e Wq[e][d1]*Wk[e][d2]
//   blk >= 256: m[e][c]     = sum_d Wih[e][d]*Wv[d][c]
__global__ __launch_bounds__(256, 4) void pre_kernel(
    const float* __restrict__ Wq, const float* __restrict__ Wk,
    const float* __restrict__ Wih, const float* __restrict__ Wv,
    float* __restrict__ wqkT, float* __restrict__ mf32)
{
  __shared__ float sh[256];
  const int blk = blockIdx.x, t = threadIdx.x;
  if(blk < 256){
    const int d2 = blk;
    sh[t] = Wk[(size_t)t * 256 + d2];
    __syncthreads();
    float acc = 0.f;
    #pragma unroll 8
    for(int e = 0; e < 256; ++e) acc += sh[e] * Wq[(size_t)e * 256 + t];
    wqkT[(size_t)d2 * 256 + t] = acc * 0.0625f;
  } else {
    const int e = blk - 256;
    sh[t] = Wih[(size_t)e * 256 + t];
    __syncthreads();
    float acc = 0.f;
    #pragma unroll 8
    for(int d = 0; d < 256; ++d) acc += sh[d] * Wv[(size_t)d * 256 + t];
    mf32[(size_t)e * 256 + t] = acc;
  }
}

// ---- merged weight pack: W(E=ET*16, K) fp32 row-major -> bf16 MFMA fragments
struct PackDesc {
  const float* src[5];
  unsigned short* dst[5];
  int ET[5];
  int K[5];
  int blkStart[6];
};

__global__ void pack_all_kernel(PackDesc pd){
  int blk = blockIdx.x;
  int seg = 0;
  #pragma unroll
  for(int i = 1; i < 5; ++i) if(blk >= pd.blkStart[i]) seg = i;
  int tid = (blk - pd.blkStart[seg]) * 256 + threadIdx.x;
  int ET = pd.ET[seg], K = pd.K[seg];
  if(tid >= ET * 16 * K) return;
  int i    = tid & 7;
  int lane = (tid >> 3) & 63;
  int rest = tid >> 9;
  int et = rest % ET;
  int kk = rest / ET;
  int row = et * 16 + (lane & 15);
  int col = kk * 32 + ((lane >> 4) << 3) + i;
  pd.dst[seg][tid] = f2bf(pd.src[seg][(size_t)row * K + col]);
}

// LN(inputs) -> x (bf16 row-major). Pure streaming, no LDS.
__global__ __launch_bounds__(256, 4) void ln_kernel(
    const float* __restrict__ inp, const float* __restrict__ g, const float* __restrict__ bta,
    unsigned short* __restrict__ x)
{
  const int t = threadIdx.x, w = t >> 6, l = t & 63;
  const size_t row0 = (size_t)blockIdx.x * 64;
  const int li = l & 15, lg = l >> 4;

  float4 gg[4], bb[4];
  #pragma unroll
  for(int q = 0; q < 4; ++q){
    gg[q] = ((const float4*)g)[li + q * 16];
    bb[q] = ((const float4*)bta)[li + q * 16];
  }
  #pragma unroll
  for(int rr = 0; rr < 4; ++rr){
    int r = w * 16 + rr * 4 + lg;
    const float4* rp = (const float4*)(inp + (row0 + r) * DD);
    float4 xv[4];
    #pragma unroll
    for(int q = 0; q < 4; ++q) xv[q] = rp[li + q * 16];
    float s1 = 0.f, s2 = 0.f;
    #pragma unroll
    for(int q = 0; q < 4; ++q){
      s1 += xv[q].x + xv[q].y + xv[q].z + xv[q].w;
      s2 += xv[q].x*xv[q].x + xv[q].y*xv[q].y + xv[q].z*xv[q].z + xv[q].w*xv[q].w;
    }
    #pragma unroll
    for(int o = 8; o >= 1; o >>= 1){ s1 += __shfl_xor(s1, o); s2 += __shfl_xor(s2, o); }
    float mean = s1 * (1.0f/256.0f);
    float inv  = rsqrtf(s2 * (1.0f/256.0f) - mean*mean + 1e-5f);
    #pragma unroll
    for(int q = 0; q < 4; ++q){
      float y0 = (xv[q].x-mean)*inv*gg[q].x + bb[q].x;
      float y1 = (xv[q].y-mean)*inv*gg[q].y + bb[q].y;
      float y2 = (xv[q].z-mean)*inv*gg[q].z + bb[q].z;
      float y3 = (xv[q].w-mean)*inv*gg[q].w + bb[q].w;
      *(uint2*)((char*)x + (row0 + r) * 512 + q * 128 + li * 8) =
          make_uint2(pk2(y0,y1), pk2(y2,y3));
    }
  }
}

// slots0 = mu + exp(log_sigma)*noise ; qk = LN_slots(slots0) @ Wqk
__global__ __launch_bounds__(256, 1) void init_kernel(
    const float* __restrict__ noise, const float* __restrict__ mu, const float* __restrict__ lsg,
    const float* __restrict__ lng, const float* __restrict__ lnb,
    const short8* __restrict__ wqkp, float* __restrict__ slots, float* __restrict__ qbuf)
{
  const int b = blockIdx.x, t = threadIdx.x, w = t >> 6, l = t & 63;
  __shared__ float SLN[SS * DD];
  __shared__ unsigned short A1[16 * DD];
  float muv = mu[t];
  float sgv = __expf(lsg[t]);
  #pragma unroll
  for(int s = 0; s < SS; ++s){
    float v = muv + sgv * noise[(size_t)b * 2048 + s * 256 + t];
    slots[(size_t)b * 2048 + s * 256 + t] = v;
    SLN[s * 256 + t] = v;
  }
  __syncthreads();
  float4 g4 = ((const float4*)lng)[l], bb4 = ((const float4*)lnb)[l];
  for(int sh = 0; sh < 2; ++sh){
    int s = w * 2 + sh;
    float4 x4 = ((const float4*)(SLN + s * 256))[l];
    float s1 = x4.x + x4.y + x4.z + x4.w;
    float s2 = x4.x*x4.x + x4.y*x4.y + x4.z*x4.z + x4.w*x4.w;
    #pragma unroll
    for(int o = 32; o >= 1; o >>= 1){ s1 += __shfl_xor(s1, o); s2 += __shfl_xor(s2, o); }
    float mean = s1 * (1.0f/256.0f);
    float inv  = rsqrtf(s2 * (1.0f/256.0f) - mean*mean + 1e-5f);
    float y0 = (x4.x-mean)*inv*g4.x + bb4.x;
    float y1 = (x4.y-mean)*inv*g4.y + bb4.y;
    float y2 = (x4.z-mean)*inv*g4.z + bb4.z;
    float y3 = (x4.w-mean)*inv*g4.w + bb4.w;
    int byte = s * 512 + ((l * 8) ^ ((s & 7) << 4));
    *(uint2*)((char*)A1 + byte) = make_uint2(pk2(y0,y1), pk2(y2,y3));
  }
  __syncthreads();
  const int m = l & 15;
  short8 af[8];
  #pragma unroll
  for(int kk = 0; kk < 8; ++kk){
    int ab = m * 512 + (((kk * 64) + ((l >> 4) << 4)) ^ ((m & 7) << 4));
    af[kk] = *(const short8*)((const char*)A1 + ab);
  }
  #pragma unroll
  for(int i = 0; i < 4; ++i){
    int et = w + i * 4;
    f32x4 c = (f32x4){0,0,0,0};
    #pragma unroll
    for(int kk = 0; kk < 8; ++kk) c = MFMA(af[kk], wqkp[((kk * 16 + et) << 6) + l], c);
    int e = et * 16 + (l & 15);
    #pragma unroll
    for(int j = 0; j < 4; ++j){
      int s = ((l >> 4) << 2) + j;
      if(s < 8) qbuf[(size_t)b * 2048 + s * 256 + e] = c[j];
    }
  }
}

// MFMA flash partials over 64-row chunks (block's chunk stays L2-resident
// between the QK read and the PV re-read). ls and xv alias one 32KB arena.
__global__ __launch_bounds__(256, 3) void attn_kernel(
    const unsigned short* __restrict__ x_, const float* __restrict__ qbuf,
    float* __restrict__ pupd, float* __restrict__ pms)
{
  const int blk = blockIdx.x;
  const int b = blk >> 6, c = blk & 63;
  const int t = threadIdx.x, w = t >> 6, l = t & 63;
  __shared__ __align__(16) char SMEM[32768];
  float* ls = (float*)SMEM;          // 8 * 68 * 4 = 2176 B
  char*  xv = SMEM;                  // 256d * 128B = 32768 B (aliases ls)

  const int m = l & 15, lg = l >> 4;
  short8 aq[8];
  #pragma unroll
  for(int kk = 0; kk < 8; ++kk){
    if(m < 8){
      const float* qp = qbuf + (size_t)b * 2048 + m * 256 + kk * 32 + (lg << 3);
      float4 qa = *(const float4*)qp;
      float4 qb = *(const float4*)(qp + 4);
      int4 pv = make_int4((int)pk2(qa.x,qa.y), (int)pk2(qa.z,qa.w),
                          (int)pk2(qb.x,qb.y), (int)pk2(qb.z,qb.w));
      aq[kk] = __builtin_bit_cast(short8, pv);
    } else {
      aq[kk] = (short8){0,0,0,0,0,0,0,0};
    }
  }

  const unsigned short* xb = x_ + ((size_t)b * NN + (size_t)c * CHK) * DD;
  // QK: warp w handles n-tile nb = w*16
  {
    int nb = w * 16;
    f32x4 acc = (f32x4){0,0,0,0};
    #pragma unroll
    for(int kk = 0; kk < 8; ++kk){
      short8 bk = *(const short8*)(xb + (size_t)(nb + m) * DD + kk * 32 + (lg << 3));
      acc = MFMA(aq[kk], bk, acc);
    }
    if(l < 32){
      int s4 = lg * 4;
      #pragma unroll
      for(int j = 0; j < 4; ++j) ls[(s4 + j) * LSP3 + nb + m] = acc[j];
    }
  }
  __syncthreads();

  // softmax over the 64-chunk per slot (warp w handles slots 2w, 2w+1)
  for(int sh = 0; sh < 2; ++sh){
    int s = w * 2 + sh;
    float v = ls[s * LSP3 + l];
    float mx = v;
    #pragma unroll
    for(int o = 32; o >= 1; o >>= 1) mx = fmaxf(mx, __shfl_xor(mx, o));
    float e0 = __expf(v - mx);
    float sm = e0;
    #pragma unroll
    for(int o = 32; o >= 1; o >>= 1) sm += __shfl_xor(sm, o);
    ls[s * LSP3 + l] = e0;
    if(l == 0){
      pms[(((size_t)b * 64 + c) * 8 + s) * 2    ] = mx;
      pms[(((size_t)b * 64 + c) * 8 + s) * 2 + 1] = sm;
    }
  }
  __syncthreads();

  // P fragments (rows m>=8 zero)
  short8 pa[2];
  #pragma unroll
  for(int kk = 0; kk < 2; ++kk){
    if(m < 8){
      const float* pp = ls + m * LSP3 + kk * 32 + (lg << 3);
      int4 pv = make_int4((int)pk2(pp[0],pp[1]), (int)pk2(pp[2],pp[3]),
                          (int)pk2(pp[4],pp[5]), (int)pk2(pp[6],pp[7]));
      pa[kk] = __builtin_bit_cast(short8, pv);
    } else {
      pa[kk] = (short8){0,0,0,0,0,0,0,0};
    }
  }
  __syncthreads();   // ls fully consumed; xv (alias) may now be written

  // PV: single 64-n subtile; warp-private staging (L2-hot re-read, no barriers).
  f32x4 acc[4];
  #pragma unroll
  for(int dt = 0; dt < 4; ++dt) acc[dt] = (f32x4){0,0,0,0};
  const int p = t & 31, db = t >> 5;
  {
    const unsigned short* rA = xb + (size_t)(2 * p) * DD + db * 32;
    const unsigned short* rB = rA + DD;
    uint4 VA[4], VB[4];
    VA[0] = *(const uint4*)(rA);      VB[0] = *(const uint4*)(rB);
    VA[1] = *(const uint4*)(rA + 8);  VB[1] = *(const uint4*)(rB + 8);
    VA[2] = *(const uint4*)(rA + 16); VB[2] = *(const uint4*)(rB + 16);
    VA[3] = *(const uint4*)(rA + 24); VB[3] = *(const uint4*)(rB + 24);
    #pragma unroll
    for(int q = 0; q < 4; ++q){
      unsigned int wa[4] = {VA[q].x, VA[q].y, VA[q].z, VA[q].w};
      unsigned int wb[4] = {VB[q].x, VB[q].y, VB[q].z, VB[q].w};
      #pragma unroll
      for(int h = 0; h < 4; ++h){
        int d0 = db * 32 + q * 8 + h * 2;
        unsigned int a = wa[h], bv = wb[h];
        unsigned int v0 = (a & 0xFFFFu) | (bv << 16);
        unsigned int v1 = (a >> 16) | (bv & 0xFFFF0000u);
        *(unsigned int*)(xv + d0 * 128 + ((p * 4) ^ ((d0 & 7) << 4))) = v0;
        int d1 = d0 + 1;
        *(unsigned int*)(xv + d1 * 128 + ((p * 4) ^ ((d1 & 7) << 4))) = v1;
      }
    }
  }
  __builtin_amdgcn_s_setprio(1);
  #pragma unroll
  for(int kkloc = 0; kkloc < 2; ++kkloc){
    #pragma unroll
    for(int dt = 0; dt < 4; ++dt){
      int d = w * 64 + dt * 16 + m;
      short8 bv = *(const short8*)(xv + d * 128 + ((kkloc * 64 + lg * 16) ^ ((d & 7) << 4)));
      acc[dt] = MFMA(pa[kkloc], bv, acc[dt]);
    }
  }
  __builtin_amdgcn_s_setprio(0);

  if(l < 32){
    int s4 = lg * 4;
    #pragma unroll
    for(int dt = 0; dt < 4; ++dt){
      int d0 = w * 64 + dt * 16;
      #pragma unroll
      for(int j = 0; j < 4; ++j)
        pupd[((size_t)b * 64 + c) * 2048 + (s4 + j) * 256 + d0 + m] = acc[dt][j];
    }
  }
}

// Combine PX partials (64 chunks) -> PX/Z ; GRU ; residual MLP ; slots ; LN ; next qk
__global__ __launch_bounds__(1024, 1) void update_kernel(
    const float* __restrict__ pupd, const float* __restrict__ pms,
    float* __restrict__ slots, float* __restrict__ qbuf,
    const short8* __restrict__ mp, const short8* __restrict__ whh,
    const float* __restrict__ bih, const float* __restrict__ bhh,
    const short8* __restrict__ w1p, const float* __restrict__ b1v,
    const short8* __restrict__ w2p, const float* __restrict__ b2v,
    const float* __restrict__ lnsg, const float* __restrict__ lnsb,
    const float* __restrict__ lnmg, const float* __restrict__ lnmb,
    const short8* __restrict__ wqkp,
    float* __restrict__ dout, const int last)
{
  const int b = blockIdx.x, t = threadIdx.x, w = t >> 6, l = t & 63;
  __shared__ unsigned short A1[16 * 256];
  __shared__ unsigned short A2[16 * 256];
  __shared__ unsigned short A3[16 * 512];
  __shared__ float GR[8 * 256], GZ[8 * 256], GXN[8 * 256], GHN[8 * 256];
  __shared__ float SL[8 * 256];
  __shared__ float PMS[1024];

  PMS[t] = pms[(size_t)b * 1024 + t];
  __syncthreads();

  const int col = t & 255, sg = t >> 8;
  float upd[2], pv[2];
  #pragma unroll
  for(int ss = 0; ss < 2; ++ss){
    int s = sg * 2 + ss;
    float mx = -1e30f;
    #pragma unroll 8
    for(int cc = 0; cc < 64; ++cc) mx = fmaxf(mx, PMS[(cc * 8 + s) * 2]);
    float Z = 0.f, u = 0.f;
    #pragma unroll 8
    for(int cc = 0; cc < 64; ++cc){
      float e = __expf(PMS[(cc * 8 + s) * 2] - mx);
      Z += e * PMS[(cc * 8 + s) * 2 + 1];
      u += e * pupd[((size_t)b * 64 + cc) * 2048 + s * 256 + col];
    }
    upd[ss] = u / Z;
    pv[ss]  = slots[(size_t)b * 2048 + s * 256 + col];
  }
  #pragma unroll
  for(int ss = 0; ss < 2; ++ss){
    int s = sg * 2 + ss;
    int byte = s * 512 + ((col * 2) ^ ((s & 7) << 4));
    *(unsigned short*)((char*)A1 + byte) = f2bf(upd[ss]);
    *(unsigned short*)((char*)A2 + byte) = f2bf(pv[ss]);
  }
  __syncthreads();

  {
    const int mq = l & 15;
    short8 a1f[8], a2f[8];
    #pragma unroll
    for(int kk = 0; kk < 8; ++kk){
      int ab = mq * 512 + (((kk * 64) + ((l >> 4) << 4)) ^ ((mq & 7) << 4));
      a1f[kk] = *(const short8*)((const char*)A1 + ab);
      a2f[kk] = *(const short8*)((const char*)A2 + ab);
    }
    #pragma unroll
    for(int i = 0; i < 3; ++i){
      int et = w + i * 16;
      f32x4 c1 = (f32x4){0,0,0,0}, c2 = (f32x4){0,0,0,0};
      #pragma unroll
      for(int kk = 0; kk < 8; ++kk){
        c1 = MFMA(a1f[kk], mp[((kk * 48 + et) << 6) + l], c1);
        c2 = MFMA(a2f[kk], whh[((kk * 48 + et) << 6) + l], c2);
      }
      int e = et * 16 + (l & 15);
      float xb = bih[e], hb = bhh[e];
      #pragma unroll
      for(int j = 0; j < 4; ++j){
        int s = ((l >> 4) << 2) + j;
        if(s < 8){
          float xx = c1[j] + xb, h = c2[j] + hb;
          if(i == 0)      GR[s * 256 + e      ] = 1.f/(1.f + __expf(-(xx + h)));
          else if(i == 1) GZ[s * 256 + (e-256)] = 1.f/(1.f + __expf(-(xx + h)));
          else { GXN[s * 256 + (e-512)] = xx; GHN[s * 256 + (e-512)] = h; }
        }
      }
    }
  }
  __syncthreads();

  #pragma unroll
  for(int ss = 0; ss < 2; ++ss){
    int s = sg * 2 + ss, idx = s * 256 + col;
    float r = GR[idx], z = GZ[idx], xn = GXN[idx], hn = GHN[idx];
    float nn = tanhf(xn + r * hn);
    SL[idx] = (1.f - z) * nn + z * pv[ss];
  }
  __syncthreads();

  if(w < 8){
    float4 g4 = ((const float4*)lnmg)[l], bb4 = ((const float4*)lnmb)[l];
    int s = w;
    float4 x4 = ((const float4*)(SL + s * 256))[l];
    float s1 = x4.x + x4.y + x4.z + x4.w;
    float s2 = x4.x*x4.x + x4.y*x4.y + x4.z*x4.z + x4.w*x4.w;
    #pragma unroll
    for(int o = 32; o >= 1; o >>= 1){ s1 += __shfl_xor(s1, o); s2 += __shfl_xor(s2, o); }
    float mean = s1 * (1.0f/256.0f);
    float inv  = rsqrtf(s2 * (1.0f/256.0f) - mean*mean + 1e-5f);
    float y0 = (x4.x-mean)*inv*g4.x + bb4.x;
    float y1 = (x4.y-mean)*inv*g4.y + bb4.y;
    float y2 = (x4.z-mean)*inv*g4.z + bb4.z;
    float y3 = (x4.w-mean)*inv*g4.w + bb4.w;
    int byte = s * 512 + ((l * 8) ^ ((s & 7) << 4));
    *(uint2*)((char*)A1 + byte) = make_uint2(pk2(y0,y1), pk2(y2,y3));
  }
  __syncthreads();

  {
    const int mq = l & 15;
    short8 af[8];
    #pragma unroll
    for(int kk = 0; kk < 8; ++kk){
      int ab = mq * 512 + (((kk * 64) + ((l >> 4) << 4)) ^ ((mq & 7) << 4));
      af[kk] = *(const short8*)((const char*)A1 + ab);
    }
    #pragma unroll
    for(int i = 0; i < 2; ++i){
      int et = w + i * 16;
      f32x4 cc = (f32x4){0,0,0,0};
      #pragma unroll
      for(int kk = 0; kk < 8; ++kk) cc = MFMA(af[kk], w1p[((kk * 32 + et) << 6) + l], cc);
      int e = et * 16 + (l & 15);
      float bb = b1v[e];
      #pragma unroll
      for(int j = 0; j < 4; ++j){
        int s = ((l >> 4) << 2) + j;
        if(s < 8){
          float h = fmaxf(cc[j] + bb, 0.f);
          int byte = s * 1024 + ((e * 2) ^ ((s & 7) << 4));
          *(unsigned short*)((char*)A3 + byte) = f2bf(h);
        }
      }
    }
  }
  __syncthreads();

  {
    const int mq = l & 15;
    short8 af[16];
    #pragma unroll
    for(int kk = 0; kk < 16; ++kk){
      int ab = mq * 1024 + (((kk * 64) + ((l >> 4) << 4)) ^ ((mq & 7) << 4));
      af[kk] = *(const short8*)((const char*)A3 + ab);
    }
    {
      int et = w;
      f32x4 cc = (f32x4){0,0,0,0};
      #pragma unroll
      for(int kk = 0; kk < 16; ++kk) cc = MFMA(af[kk], w2p[((kk * 16 + et) << 6) + l], cc);
      int e = et * 16 + (l & 15);
      float bb = b2v[e];
      #pragma unroll
      for(int j = 0; j < 4; ++j){
        int s = ((l >> 4) << 2) + j;
        if(s < 8) GR[s * 256 + e] = SL[s * 256 + e] + cc[j] + bb;
      }
    }
  }
  __syncthreads();

  for(int i = t; i < 2048; i += 1024){
    float v = GR[i];
    slots[(size_t)b * 2048 + i] = v;
    if(last) dout[(size_t)b * 2048 + i] = v;
  }
  if(w < 8){
    float4 g4 = ((const float4*)lnsg)[l], bb4 = ((const float4*)lnsb)[l];
    int s = w;
    float4 x4 = ((const float4*)(GR + s * 256))[l];
    float s1 = x4.x + x4.y + x4.z + x4.w;
    float s2 = x4.x*x4.x + x4.y*x4.y + x4.z*x4.z + x4.w*x4.w;
    #pragma unroll
    for(int o = 32; o >= 1; o >>= 1){ s1 += __shfl_xor(s1, o); s2 += __shfl_xor(s2, o); }
    float mean = s1 * (1.0f/256.0f);
    float inv  = rsqrtf(s2 * (1.0f/256.0f) - mean*mean + 1e-5f);
    float y0 = (x4.x-mean)*inv*g4.x + bb4.x;
    float y1 = (x4.y-mean)*inv*g4.y + bb4.y;
    float y2 = (x4.z-mean)*inv*g4.z + bb4.z;
    float y3 = (x4.w-mean)*inv*g4.w + bb4.w;
    int byte = s * 512 + ((l * 8) ^ ((s & 7) << 4));
    *(uint2*)((char*)A1 + byte) = make_uint2(pk2(y0,y1), pk2(y2,y3));
  }
  __syncthreads();
  {
    const int mq = l & 15;
    short8 af[8];
    #pragma unroll
    for(int kk = 0; kk < 8; ++kk){
      int ab = mq * 512 + (((kk * 64) + ((l >> 4) << 4)) ^ ((mq & 7) << 4));
      af[kk] = *(const short8*)((const char*)A1 + ab);
    }
    {
      int et = w;
      f32x4 cc = (f32x4){0,0,0,0};
      #pragma unroll
      for(int kk = 0; kk < 8; ++kk) cc = MFMA(af[kk], wqkp[((kk * 16 + et) << 6) + l], cc);
      int e = et * 16 + (l & 15);
      #pragma unroll
      for(int j = 0; j < 4; ++j){
        int s = ((l >> 4) << 2) + j;
        if(s < 8) qbuf[(size_t)b * 2048 + s * 256 + e] = cc[j];
      }
    }
  }
}

extern "C" void kernel_launch(void* const* d_in, const int* in_sizes, int n_in,
                              void* d_out, int out_size, void* d_ws, size_t ws_size,
                              hipStream_t stream)
{
  const float* inp   = (const float*)d_in[0];
  const float* noise = (const float*)d_in[1];
  const float* mu    = (const float*)d_in[2];
  const float* lsg   = (const float*)d_in[3];
  const float* lngi  = (const float*)d_in[4];
  const float* lnbi  = (const float*)d_in[5];
  const float* lngs  = (const float*)d_in[6];
  const float* lnbs  = (const float*)d_in[7];
  const float* lngm  = (const float*)d_in[8];
  const float* lnbm  = (const float*)d_in[9];
  const float* Wq    = (const float*)d_in[10];
  const float* Wk    = (const float*)d_in[11];
  const float* Wv    = (const float*)d_in[12];
  const float* Wih   = (const float*)d_in[13];
  const float* Whh   = (const float*)d_in[14];
  const float* bih   = (const float*)d_in[15];
  const float* bhh   = (const float*)d_in[16];
  const float* W1    = (const float*)d_in[17];
  const float* b1    = (const float*)d_in[18];
  const float* W2    = (const float*)d_in[19];
  const float* b2    = (const float*)d_in[20];
  float* dout = (float*)d_out;

  char* ws = (char*)d_ws;
  size_t off = 0;
  unsigned short* x   = (unsigned short*)(ws + off); off += (size_t)BB*NN*DD*2;
  short8* wqkp= (short8*)(ws + off); off += (size_t)256*256*2;
  short8* mp  = (short8*)(ws + off); off += (size_t)768*256*2;
  short8* whhp= (short8*)(ws + off); off += (size_t)768*256*2;
  short8* w1p = (short8*)(ws + off); off += (size_t)512*256*2;
  short8* w2p = (short8*)(ws + off); off += (size_t)256*512*2;
  float* wqkT = (float*)(ws + off);  off += (size_t)256*256*4;
  float* mf32 = (float*)(ws + off);  off += (size_t)768*256*4;
  float* qbuf = (float*)(ws + off);  off += (size_t)512*256*4;
  float* slots= (float*)(ws + off);  off += (size_t)512*256*4;
  float* pupd = (float*)(ws + off);  off += (size_t)BB*NCH*2048*4;
  float* pms  = (float*)(ws + off);  off += (size_t)BB*NCH*8*2*4;

  pre_kernel<<<1024, 256, 0, stream>>>(Wq, Wk, Wih, Wv, wqkT, mf32);

  PackDesc pd;
  const float* srcs[5] = {wqkT, mf32, Whh, W1, W2};
  unsigned short* dsts[5] = {(unsigned short*)wqkp, (unsigned short*)mp,
                             (unsigned short*)whhp, (unsigned short*)w1p,
                             (unsigned short*)w2p};
  int ets[5] = {16, 48, 48, 32, 16};
  int ks [5] = {256, 256, 256, 256, 512};
  int cum = 0;
  for(int i = 0; i < 5; ++i){
    pd.src[i] = srcs[i]; pd.dst[i] = dsts[i]; pd.ET[i] = ets[i]; pd.K[i] = ks[i];
    pd.blkStart[i] = cum;
    cum += (ets[i] * 16 * ks[i] + 255) / 256;
  }
  pd.blkStart[5] = cum;
  pack_all_kernel<<<cum, 256, 0, stream>>>(pd);

  ln_kernel<<<4096, 256, 0, stream>>>(inp, lngi, lnbi, x);
  init_kernel<<<64, 256, 0, stream>>>(noise, mu, lsg, lngs, lnbs, wqkp, slots, qbuf);

  for(int it = 0; it < 3; ++it){
    attn_kernel<<<BB * NCH, 256, 0, stream>>>(x, qbuf, pupd, pms);
    update_kernel<<<64, 1024, 0, stream>>>(pupd, pms, slots, qbuf, mp, whhp,
        bih, bhh, w1p, b1, w2p, b2, lngs, lnbs, lngm, lnbm, wqkp, dout, (it == 2) ? 1 : 0);
  }
}

// Round 17
// 338.688 us; speedup vs baseline: 1.2408x; 1.2408x over previous
//
#include <hip/hip_runtime.h>

// Slot attention, MI355X. B=64,N=4096,S=8,D=256,H=512,ITERS=3.
// K,V never materialized (Wqk = scale*Wq^T@Wk, M = W_ih@Wv folded).
// attn: 256-row chunks (1024 blocks), ls/xv aliased in one 32KB LDS arena,
// warp-private PV staging with prefetch, setprio around PV MFMAs.
#define BB 64
#define NN 4096
#define SS 8
#define DD 256
#define HH 512
#define NCH 16
#define CHK 256
#define LSP2 260  // padded row stride (f32) for logits LDS

typedef __attribute__((ext_vector_type(4))) float f32x4;
typedef __attribute__((ext_vector_type(8))) short short8;
typedef __attribute__((ext_vector_type(8))) __bf16 bf16x8;

static __device__ __forceinline__ f32x4 MFMA(short8 a, short8 b, f32x4 c){
  return __builtin_amdgcn_mfma_f32_16x16x32_bf16(
      __builtin_bit_cast(bf16x8, a), __builtin_bit_cast(bf16x8, b), c, 0, 0, 0);
}

static __device__ __forceinline__ unsigned short f2bf(float f){
  unsigned int x = __builtin_bit_cast(unsigned int, f);
  x += 0x7FFFu + ((x >> 16) & 1u);
  return (unsigned short)(x >> 16);
}

static __device__ __forceinline__ unsigned int pk2(float a, float b){
  return (unsigned int)f2bf(a) | ((unsigned int)f2bf(b) << 16);
}

// ---- merged precompute:
//   blk <  256: wqkT[d2][d1] = scale * sum_e Wq[e][d1]*Wk[e][d2]
//   blk >= 256: m[e][c]     = sum_d Wih[e][d]*Wv[d][c]
__global__ __launch_bounds__(256, 4) void pre_kernel(
    const float* __restrict__ Wq, const float* __restrict__ Wk,
    const float* __restrict__ Wih, const float* __restrict__ Wv,
    float* __restrict__ wqkT, float* __restrict__ mf32)
{
  __shared__ float sh[256];
  const int blk = blockIdx.x, t = threadIdx.x;
  if(blk < 256){
    const int d2 = blk;
    sh[t] = Wk[(size_t)t * 256 + d2];
    __syncthreads();
    float acc = 0.f;
    #pragma unroll 8
    for(int e = 0; e < 256; ++e) acc += sh[e] * Wq[(size_t)e * 256 + t];
    wqkT[(size_t)d2 * 256 + t] = acc * 0.0625f;
  } else {
    const int e = blk - 256;
    sh[t] = Wih[(size_t)e * 256 + t];
    __syncthreads();
    float acc = 0.f;
    #pragma unroll 8
    for(int d = 0; d < 256; ++d) acc += sh[d] * Wv[(size_t)d * 256 + t];
    mf32[(size_t)e * 256 + t] = acc;
  }
}

// ---- merged weight pack: W(E=ET*16, K) fp32 row-major -> bf16 MFMA fragments
struct PackDesc {
  const float* src[5];
  unsigned short* dst[5];
  int ET[5];
  int K[5];
  int blkStart[6];
};

__global__ void pack_all_kernel(PackDesc pd){
  int blk = blockIdx.x;
  int seg = 0;
  #pragma unroll
  for(int i = 1; i < 5; ++i) if(blk >= pd.blkStart[i]) seg = i;
  int tid = (blk - pd.blkStart[seg]) * 256 + threadIdx.x;
  int ET = pd.ET[seg], K = pd.K[seg];
  if(tid >= ET * 16 * K) return;
  int i    = tid & 7;
  int lane = (tid >> 3) & 63;
  int rest = tid >> 9;
  int et = rest % ET;
  int kk = rest / ET;
  int row = et * 16 + (lane & 15);
  int col = kk * 32 + ((lane >> 4) << 3) + i;
  pd.dst[seg][tid] = f2bf(pd.src[seg][(size_t)row * K + col]);
}

// LN(inputs) -> x (bf16 row-major). Pure streaming, no LDS.
__global__ __launch_bounds__(256, 4) void ln_kernel(
    const float* __restrict__ inp, const float* __restrict__ g, const float* __restrict__ bta,
    unsigned short* __restrict__ x)
{
  const int t = threadIdx.x, w = t >> 6, l = t & 63;
  const size_t row0 = (size_t)blockIdx.x * 64;
  const int li = l & 15, lg = l >> 4;

  float4 gg[4], bb[4];
  #pragma unroll
  for(int q = 0; q < 4; ++q){
    gg[q] = ((const float4*)g)[li + q * 16];
    bb[q] = ((const float4*)bta)[li + q * 16];
  }
  #pragma unroll
  for(int rr = 0; rr < 4; ++rr){
    int r = w * 16 + rr * 4 + lg;
    const float4* rp = (const float4*)(inp + (row0 + r) * DD);
    float4 xv[4];
    #pragma unroll
    for(int q = 0; q < 4; ++q) xv[q] = rp[li + q * 16];
    float s1 = 0.f, s2 = 0.f;
    #pragma unroll
    for(int q = 0; q < 4; ++q){
      s1 += xv[q].x + xv[q].y + xv[q].z + xv[q].w;
      s2 += xv[q].x*xv[q].x + xv[q].y*xv[q].y + xv[q].z*xv[q].z + xv[q].w*xv[q].w;
    }
    #pragma unroll
    for(int o = 8; o >= 1; o >>= 1){ s1 += __shfl_xor(s1, o); s2 += __shfl_xor(s2, o); }
    float mean = s1 * (1.0f/256.0f);
    float inv  = rsqrtf(s2 * (1.0f/256.0f) - mean*mean + 1e-5f);
    #pragma unroll
    for(int q = 0; q < 4; ++q){
      float y0 = (xv[q].x-mean)*inv*gg[q].x + bb[q].x;
      float y1 = (xv[q].y-mean)*inv*gg[q].y + bb[q].y;
      float y2 = (xv[q].z-mean)*inv*gg[q].z + bb[q].z;
      float y3 = (xv[q].w-mean)*inv*gg[q].w + bb[q].w;
      *(uint2*)((char*)x + (row0 + r) * 512 + q * 128 + li * 8) =
          make_uint2(pk2(y0,y1), pk2(y2,y3));
    }
  }
}

// slots0 = mu + exp(log_sigma)*noise ; qk = LN_slots(slots0) @ Wqk
__global__ __launch_bounds__(256, 1) void init_kernel(
    const float* __restrict__ noise, const float* __restrict__ mu, const float* __restrict__ lsg,
    const float* __restrict__ lng, const float* __restrict__ lnb,
    const short8* __restrict__ wqkp, float* __restrict__ slots, float* __restrict__ qbuf)
{
  const int b = blockIdx.x, t = threadIdx.x, w = t >> 6, l = t & 63;
  __shared__ float SLN[SS * DD];
  __shared__ unsigned short A1[16 * DD];
  float muv = mu[t];
  float sgv = __expf(lsg[t]);
  #pragma unroll
  for(int s = 0; s < SS; ++s){
    float v = muv + sgv * noise[(size_t)b * 2048 + s * 256 + t];
    slots[(size_t)b * 2048 + s * 256 + t] = v;
    SLN[s * 256 + t] = v;
  }
  __syncthreads();
  float4 g4 = ((const float4*)lng)[l], bb4 = ((const float4*)lnb)[l];
  for(int sh = 0; sh < 2; ++sh){
    int s = w * 2 + sh;
    float4 x4 = ((const float4*)(SLN + s * 256))[l];
    float s1 = x4.x + x4.y + x4.z + x4.w;
    float s2 = x4.x*x4.x + x4.y*x4.y + x4.z*x4.z + x4.w*x4.w;
    #pragma unroll
    for(int o = 32; o >= 1; o >>= 1){ s1 += __shfl_xor(s1, o); s2 += __shfl_xor(s2, o); }
    float mean = s1 * (1.0f/256.0f);
    float inv  = rsqrtf(s2 * (1.0f/256.0f) - mean*mean + 1e-5f);
    float y0 = (x4.x-mean)*inv*g4.x + bb4.x;
    float y1 = (x4.y-mean)*inv*g4.y + bb4.y;
    float y2 = (x4.z-mean)*inv*g4.z + bb4.z;
    float y3 = (x4.w-mean)*inv*g4.w + bb4.w;
    int byte = s * 512 + ((l * 8) ^ ((s & 7) << 4));
    *(uint2*)((char*)A1 + byte) = make_uint2(pk2(y0,y1), pk2(y2,y3));
  }
  __syncthreads();
  const int m = l & 15;
  short8 af[8];
  #pragma unroll
  for(int kk = 0; kk < 8; ++kk){
    int ab = m * 512 + (((kk * 64) + ((l >> 4) << 4)) ^ ((m & 7) << 4));
    af[kk] = *(const short8*)((const char*)A1 + ab);
  }
  #pragma unroll
  for(int i = 0; i < 4; ++i){
    int et = w + i * 4;
    f32x4 c = (f32x4){0,0,0,0};
    #pragma unroll
    for(int kk = 0; kk < 8; ++kk) c = MFMA(af[kk], wqkp[((kk * 16 + et) << 6) + l], c);
    int e = et * 16 + (l & 15);
    #pragma unroll
    for(int j = 0; j < 4; ++j){
      int s = ((l >> 4) << 2) + j;
      if(s < 8) qbuf[(size_t)b * 2048 + s * 256 + e] = c[j];
    }
  }
}

// MFMA flash partials over 256-row chunks: logits = qk@x^T, softmax, PX = P@x.
// ls (logits, 8.3KB) and xv (transpose tile, 32KB) alias one arena: pa fragments
// are fully in registers before xv overwrites ls (single barrier guards it).
__global__ __launch_bounds__(256, 3) void attn_kernel(
    const unsigned short* __restrict__ x_, const float* __restrict__ qbuf,
    float* __restrict__ pupd, float* __restrict__ pms)
{
  const int blk = blockIdx.x;
  const int b = blk >> 4, c = blk & 15;
  const int t = threadIdx.x, w = t >> 6, l = t & 63;
  __shared__ __align__(16) char SMEM[32768];
  float* ls = (float*)SMEM;          // 8 * 260 * 4 = 8320 B
  char*  xv = SMEM;                  // 256d * 128B = 32768 B (aliases ls)

  const int m = l & 15, lg = l >> 4;
  short8 aq[8];
  #pragma unroll
  for(int kk = 0; kk < 8; ++kk){
    if(m < 8){
      const float* qp = qbuf + (size_t)b * 2048 + m * 256 + kk * 32 + (lg << 3);
      float4 qa = *(const float4*)qp;
      float4 qb = *(const float4*)(qp + 4);
      int4 pv = make_int4((int)pk2(qa.x,qa.y), (int)pk2(qa.z,qa.w),
                          (int)pk2(qb.x,qb.y), (int)pk2(qb.z,qb.w));
      aq[kk] = __builtin_bit_cast(short8, pv);
    } else {
      aq[kk] = (short8){0,0,0,0,0,0,0,0};
    }
  }

  const unsigned short* xb = x_ + ((size_t)b * NN + (size_t)c * CHK) * DD;
  // QK: warp w covers n-tiles w*64 .. w*64+63
  #pragma unroll
  for(int nt = 0; nt < 4; ++nt){
    int nb = w * 64 + nt * 16;
    f32x4 acc = (f32x4){0,0,0,0};
    #pragma unroll
    for(int kk = 0; kk < 8; ++kk){
      short8 bk = *(const short8*)(xb + (size_t)(nb + m) * DD + kk * 32 + (lg << 3));
      acc = MFMA(aq[kk], bk, acc);
    }
    if(l < 32){
      int s4 = lg * 4;
      #pragma unroll
      for(int j = 0; j < 4; ++j) ls[(s4 + j) * LSP2 + nb + m] = acc[j];
    }
  }
  __syncthreads();

  // softmax over the 256-chunk per slot (warp w handles slots 2w, 2w+1)
  for(int sh = 0; sh < 2; ++sh){
    int s = w * 2 + sh;
    float* base = ls + s * LSP2;
    float4 v0 = *(float4*)(base + l * 4);
    float mx = fmaxf(fmaxf(v0.x,v0.y),fmaxf(v0.z,v0.w));
    #pragma unroll
    for(int o = 32; o >= 1; o >>= 1) mx = fmaxf(mx, __shfl_xor(mx, o));
    float e0 = __expf(v0.x-mx), e1 = __expf(v0.y-mx), e2 = __expf(v0.z-mx), e3 = __expf(v0.w-mx);
    float sm = e0+e1+e2+e3;
    #pragma unroll
    for(int o = 32; o >= 1; o >>= 1) sm += __shfl_xor(sm, o);
    *(float4*)(base + l * 4) = make_float4(e0,e1,e2,e3);
    if(l == 0){
      pms[(((size_t)b * 16 + c) * 8 + s) * 2    ] = mx;
      pms[(((size_t)b * 16 + c) * 8 + s) * 2 + 1] = sm;
    }
  }
  __syncthreads();

  // P fragments (rows m>=8 zero)
  short8 pa[8];
  #pragma unroll
  for(int kk = 0; kk < 8; ++kk){
    if(m < 8){
      const float* pp = ls + m * LSP2 + kk * 32 + (lg << 3);
      int4 pv = make_int4((int)pk2(pp[0],pp[1]), (int)pk2(pp[2],pp[3]),
                          (int)pk2(pp[4],pp[5]), (int)pk2(pp[6],pp[7]));
      pa[kk] = __builtin_bit_cast(short8, pv);
    } else {
      pa[kk] = (short8){0,0,0,0,0,0,0,0};
    }
  }
  __syncthreads();   // ls fully consumed; xv (alias) may now be written

  // PV: 4 x 64-n subtiles; warp-private staging (no barriers); prefetched loads.
  f32x4 acc[4];
  #pragma unroll
  for(int dt = 0; dt < 4; ++dt) acc[dt] = (f32x4){0,0,0,0};
  const int p = t & 31, db = t >> 5;

  uint4 va0, va1, va2, va3, vb0, vb1, vb2, vb3;
  {
    const unsigned short* rA = xb + (size_t)(2 * p) * DD + db * 32;
    const unsigned short* rB = rA + DD;
    va0 = *(const uint4*)(rA);      vb0 = *(const uint4*)(rB);
    va1 = *(const uint4*)(rA + 8);  vb1 = *(const uint4*)(rB + 8);
    va2 = *(const uint4*)(rA + 16); vb2 = *(const uint4*)(rB + 16);
    va3 = *(const uint4*)(rA + 24); vb3 = *(const uint4*)(rB + 24);
  }

  for(int ng = 0; ng < 4; ++ng){
    {
      uint4 VA[4] = {va0, va1, va2, va3};
      uint4 VB[4] = {vb0, vb1, vb2, vb3};
      #pragma unroll
      for(int q = 0; q < 4; ++q){
        unsigned int wa[4] = {VA[q].x, VA[q].y, VA[q].z, VA[q].w};
        unsigned int wb[4] = {VB[q].x, VB[q].y, VB[q].z, VB[q].w};
        #pragma unroll
        for(int h = 0; h < 4; ++h){
          int d0 = db * 32 + q * 8 + h * 2;
          unsigned int a = wa[h], bv = wb[h];
          unsigned int v0 = (a & 0xFFFFu) | (bv << 16);
          unsigned int v1 = (a >> 16) | (bv & 0xFFFF0000u);
          *(unsigned int*)(xv + d0 * 128 + ((p * 4) ^ ((d0 & 7) << 4))) = v0;
          int d1 = d0 + 1;
          *(unsigned int*)(xv + d1 * 128 + ((p * 4) ^ ((d1 & 7) << 4))) = v1;
        }
      }
    }
    if(ng < 3){
      const unsigned short* rA = xb + (size_t)((ng + 1) * 64 + 2 * p) * DD + db * 32;
      const unsigned short* rB = rA + DD;
      va0 = *(const uint4*)(rA);      vb0 = *(const uint4*)(rB);
      va1 = *(const uint4*)(rA + 8);  vb1 = *(const uint4*)(rB + 8);
      va2 = *(const uint4*)(rA + 16); vb2 = *(const uint4*)(rB + 16);
      va3 = *(const uint4*)(rA + 24); vb3 = *(const uint4*)(rB + 24);
    }
    __builtin_amdgcn_s_setprio(1);
    #pragma unroll
    for(int kkloc = 0; kkloc < 2; ++kkloc){
      int kk = ng * 2 + kkloc;
      #pragma unroll
      for(int dt = 0; dt < 4; ++dt){
        int d = w * 64 + dt * 16 + m;
        short8 bv = *(const short8*)(xv + d * 128 + ((kkloc * 64 + lg * 16) ^ ((d & 7) << 4)));
        acc[dt] = MFMA(pa[kk], bv, acc[dt]);
      }
    }
    __builtin_amdgcn_s_setprio(0);
  }
  if(l < 32){
    int s4 = lg * 4;
    #pragma unroll
    for(int dt = 0; dt < 4; ++dt){
      int d0 = w * 64 + dt * 16;
      #pragma unroll
      for(int j = 0; j < 4; ++j)
        pupd[((size_t)b * 16 + c) * 2048 + (s4 + j) * 256 + d0 + m] = acc[dt][j];
    }
  }
}

// Combine PX partials (16 chunks) -> PX/Z ; GRU ; residual MLP ; slots ; LN ; next qk
__global__ __launch_bounds__(1024, 1) void update_kernel(
    const float* __restrict__ pupd, const float* __restrict__ pms,
    float* __restrict__ slots, float* __restrict__ qbuf,
    const short8* __restrict__ mp, const short8* __restrict__ whh,
    const float* __restrict__ bih, const float* __restrict__ bhh,
    const short8* __restrict__ w1p, const float* __restrict__ b1v,
    const short8* __restrict__ w2p, const float* __restrict__ b2v,
    const float* __restrict__ lnsg, const float* __restrict__ lnsb,
    const float* __restrict__ lnmg, const float* __restrict__ lnmb,
    const short8* __restrict__ wqkp,
    float* __restrict__ dout, const int last)
{
  const int b = blockIdx.x, t = threadIdx.x, w = t >> 6, l = t & 63;
  __shared__ unsigned short A1[16 * 256];
  __shared__ unsigned short A2[16 * 256];
  __shared__ unsigned short A3[16 * 512];
  __shared__ float GR[8 * 256], GZ[8 * 256], GXN[8 * 256], GHN[8 * 256];
  __shared__ float SL[8 * 256];
  __shared__ float PMS[256];

  if(t < 256) PMS[t] = pms[(size_t)b * 256 + t];
  __syncthreads();

  const int col = t & 255, sg = t >> 8;
  float upd[2], pv[2];
  #pragma unroll
  for(int ss = 0; ss < 2; ++ss){
    int s = sg * 2 + ss;
    float mx = -1e30f;
    #pragma unroll
    for(int cc = 0; cc < 16; ++cc) mx = fmaxf(mx, PMS[(cc * 8 + s) * 2]);
    float Z = 0.f, u = 0.f;
    #pragma unroll
    for(int cc = 0; cc < 16; ++cc){
      float e = __expf(PMS[(cc * 8 + s) * 2] - mx);
      Z += e * PMS[(cc * 8 + s) * 2 + 1];
      u += e * pupd[((size_t)b * 16 + cc) * 2048 + s * 256 + col];
    }
    upd[ss] = u / Z;
    pv[ss]  = slots[(size_t)b * 2048 + s * 256 + col];
  }
  #pragma unroll
  for(int ss = 0; ss < 2; ++ss){
    int s = sg * 2 + ss;
    int byte = s * 512 + ((col * 2) ^ ((s & 7) << 4));
    *(unsigned short*)((char*)A1 + byte) = f2bf(upd[ss]);
    *(unsigned short*)((char*)A2 + byte) = f2bf(pv[ss]);
  }
  __syncthreads();

  {
    const int mq = l & 15;
    short8 a1f[8], a2f[8];
    #pragma unroll
    for(int kk = 0; kk < 8; ++kk){
      int ab = mq * 512 + (((kk * 64) + ((l >> 4) << 4)) ^ ((mq & 7) << 4));
      a1f[kk] = *(const short8*)((const char*)A1 + ab);
      a2f[kk] = *(const short8*)((const char*)A2 + ab);
    }
    #pragma unroll
    for(int i = 0; i < 3; ++i){
      int et = w + i * 16;
      f32x4 c1 = (f32x4){0,0,0,0}, c2 = (f32x4){0,0,0,0};
      #pragma unroll
      for(int kk = 0; kk < 8; ++kk){
        c1 = MFMA(a1f[kk], mp[((kk * 48 + et) << 6) + l], c1);
        c2 = MFMA(a2f[kk], whh[((kk * 48 + et) << 6) + l], c2);
      }
      int e = et * 16 + (l & 15);
      float xb = bih[e], hb = bhh[e];
      #pragma unroll
      for(int j = 0; j < 4; ++j){
        int s = ((l >> 4) << 2) + j;
        if(s < 8){
          float xx = c1[j] + xb, h = c2[j] + hb;
          if(i == 0)      GR[s * 256 + e      ] = 1.f/(1.f + __expf(-(xx + h)));
          else if(i == 1) GZ[s * 256 + (e-256)] = 1.f/(1.f + __expf(-(xx + h)));
          else { GXN[s * 256 + (e-512)] = xx; GHN[s * 256 + (e-512)] = h; }
        }
      }
    }
  }
  __syncthreads();

  #pragma unroll
  for(int ss = 0; ss < 2; ++ss){
    int s = sg * 2 + ss, idx = s * 256 + col;
    float r = GR[idx], z = GZ[idx], xn = GXN[idx], hn = GHN[idx];
    float nn = tanhf(xn + r * hn);
    SL[idx] = (1.f - z) * nn + z * pv[ss];
  }
  __syncthreads();

  if(w < 8){
    float4 g4 = ((const float4*)lnmg)[l], bb4 = ((const float4*)lnmb)[l];
    int s = w;
    float4 x4 = ((const float4*)(SL + s * 256))[l];
    float s1 = x4.x + x4.y + x4.z + x4.w;
    float s2 = x4.x*x4.x + x4.y*x4.y + x4.z*x4.z + x4.w*x4.w;
    #pragma unroll
    for(int o = 32; o >= 1; o >>= 1){ s1 += __shfl_xor(s1, o); s2 += __shfl_xor(s2, o); }
    float mean = s1 * (1.0f/256.0f);
    float inv  = rsqrtf(s2 * (1.0f/256.0f) - mean*mean + 1e-5f);
    float y0 = (x4.x-mean)*inv*g4.x + bb4.x;
    float y1 = (x4.y-mean)*inv*g4.y + bb4.y;
    float y2 = (x4.z-mean)*inv*g4.z + bb4.z;
    float y3 = (x4.w-mean)*inv*g4.w + bb4.w;
    int byte = s * 512 + ((l * 8) ^ ((s & 7) << 4));
    *(uint2*)((char*)A1 + byte) = make_uint2(pk2(y0,y1), pk2(y2,y3));
  }
  __syncthreads();

  {
    const int mq = l & 15;
    short8 af[8];
    #pragma unroll
    for(int kk = 0; kk < 8; ++kk){
      int ab = mq * 512 + (((kk * 64) + ((l >> 4) << 4)) ^ ((mq & 7) << 4));
      af[kk] = *(const short8*)((const char*)A1 + ab);
    }
    #pragma unroll
    for(int i = 0; i < 2; ++i){
      int et = w + i * 16;
      f32x4 cc = (f32x4){0,0,0,0};
      #pragma unroll
      for(int kk = 0; kk < 8; ++kk) cc = MFMA(af[kk], w1p[((kk * 32 + et) << 6) + l], cc);
      int e = et * 16 + (l & 15);
      float bb = b1v[e];
      #pragma unroll
      for(int j = 0; j < 4; ++j){
        int s = ((l >> 4) << 2) + j;
        if(s < 8){
          float h = fmaxf(cc[j] + bb, 0.f);
          int byte = s * 1024 + ((e * 2) ^ ((s & 7) << 4));
          *(unsigned short*)((char*)A3 + byte) = f2bf(h);
        }
      }
    }
  }
  __syncthreads();

  {
    const int mq = l & 15;
    short8 af[16];
    #pragma unroll
    for(int kk = 0; kk < 16; ++kk){
      int ab = mq * 1024 + (((kk * 64) + ((l >> 4) << 4)) ^ ((mq & 7) << 4));
      af[kk] = *(const short8*)((const char*)A3 + ab);
    }
    {
      int et = w;
      f32x4 cc = (f32x4){0,0,0,0};
      #pragma unroll
      for(int kk = 0; kk < 16; ++kk) cc = MFMA(af[kk], w2p[((kk * 16 + et) << 6) + l], cc);
      int e = et * 16 + (l & 15);
      float bb = b2v[e];
      #pragma unroll
      for(int j = 0; j < 4; ++j){
        int s = ((l >> 4) << 2) + j;
        if(s < 8) GR[s * 256 + e] = SL[s * 256 + e] + cc[j] + bb;
      }
    }
  }
  __syncthreads();

  for(int i = t; i < 2048; i += 1024){
    float v = GR[i];
    slots[(size_t)b * 2048 + i] = v;
    if(last) dout[(size_t)b * 2048 + i] = v;
  }
  if(w < 8){
    float4 g4 = ((const float4*)lnsg)[l], bb4 = ((const float4*)lnsb)[l];
    int s = w;
    float4 x4 = ((const float4*)(GR + s * 256))[l];
    float s1 = x4.x + x4.y + x4.z + x4.w;
    float s2 = x4.x*x4.x + x4.y*x4.y + x4.z*x4.z + x4.w*x4.w;
    #pragma unroll
    for(int o = 32; o >= 1; o >>= 1){ s1 += __shfl_xor(s1, o); s2 += __shfl_xor(s2, o); }
    float mean = s1 * (1.0f/256.0f);
    float inv  = rsqrtf(s2 * (1.0f/256.0f) - mean*mean + 1e-5f);
    float y0 = (x4.x-mean)*inv*g4.x + bb4.x;
    float y1 = (x4.y-mean)*inv*g4.y + bb4.y;
    float y2 = (x4.z-mean)*inv*g4.z + bb4.z;
    float y3 = (x4.w-mean)*inv*g4.w + bb4.w;
    int byte = s * 512 + ((l * 8) ^ ((s & 7) << 4));
    *(uint2*)((char*)A1 + byte) = make_uint2(pk2(y0,y1), pk2(y2,y3));
  }
  __syncthreads();
  {
    const int mq = l & 15;
    short8 af[8];
    #pragma unroll
    for(int kk = 0; kk < 8; ++kk){
      int ab = mq * 512 + (((kk * 64) + ((l >> 4) << 4)) ^ ((mq & 7) << 4));
      af[kk] = *(const short8*)((const char*)A1 + ab);
    }
    {
      int et = w;
      f32x4 cc = (f32x4){0,0,0,0};
      #pragma unroll
      for(int kk = 0; kk < 8; ++kk) cc = MFMA(af[kk], wqkp[((kk * 16 + et) << 6) + l], cc);
      int e = et * 16 + (l & 15);
      #pragma unroll
      for(int j = 0; j < 4; ++j){
        int s = ((l >> 4) << 2) + j;
        if(s < 8) qbuf[(size_t)b * 2048 + s * 256 + e] = cc[j];
      }
    }
  }
}

extern "C" void kernel_launch(void* const* d_in, const int* in_sizes, int n_in,
                              void* d_out, int out_size, void* d_ws, size_t ws_size,
                              hipStream_t stream)
{
  const float* inp   = (const float*)d_in[0];
  const float* noise = (const float*)d_in[1];
  const float* mu    = (const float*)d_in[2];
  const float* lsg   = (const float*)d_in[3];
  const float* lngi  = (const float*)d_in[4];
  const float* lnbi  = (const float*)d_in[5];
  const float* lngs  = (const float*)d_in[6];
  const float* lnbs  = (const float*)d_in[7];
  const float* lngm  = (const float*)d_in[8];
  const float* lnbm  = (const float*)d_in[9];
  const float* Wq    = (const float*)d_in[10];
  const float* Wk    = (const float*)d_in[11];
  const float* Wv    = (const float*)d_in[12];
  const float* Wih   = (const float*)d_in[13];
  const float* Whh   = (const float*)d_in[14];
  const float* bih   = (const float*)d_in[15];
  const float* bhh   = (const float*)d_in[16];
  const float* W1    = (const float*)d_in[17];
  const float* b1    = (const float*)d_in[18];
  const float* W2    = (const float*)d_in[19];
  const float* b2    = (const float*)d_in[20];
  float* dout = (float*)d_out;

  char* ws = (char*)d_ws;
  size_t off = 0;
  unsigned short* x   = (unsigned short*)(ws + off); off += (size_t)BB*NN*DD*2;
  short8* wqkp= (short8*)(ws + off); off += (size_t)256*256*2;
  short8* mp  = (short8*)(ws + off); off += (size_t)768*256*2;
  short8* whhp= (short8*)(ws + off); off += (size_t)768*256*2;
  short8* w1p = (short8*)(ws + off); off += (size_t)512*256*2;
  short8* w2p = (short8*)(ws + off); off += (size_t)256*512*2;
  float* wqkT = (float*)(ws + off);  off += (size_t)256*256*4;
  float* mf32 = (float*)(ws + off);  off += (size_t)768*256*4;
  float* qbuf = (float*)(ws + off);  off += (size_t)512*256*4;
  float* slots= (float*)(ws + off);  off += (size_t)512*256*4;
  float* pupd = (float*)(ws + off);  off += (size_t)BB*NCH*2048*4;
  float* pms  = (float*)(ws + off);  off += (size_t)BB*NCH*8*2*4;

  pre_kernel<<<1024, 256, 0, stream>>>(Wq, Wk, Wih, Wv, wqkT, mf32);

  PackDesc pd;
  const float* srcs[5] = {wqkT, mf32, Whh, W1, W2};
  unsigned short* dsts[5] = {(unsigned short*)wqkp, (unsigned short*)mp,
                             (unsigned short*)whhp, (unsigned short*)w1p,
                             (unsigned short*)w2p};
  int ets[5] = {16, 48, 48, 32, 16};
  int ks [5] = {256, 256, 256, 256, 512};
  int cum = 0;
  for(int i = 0; i < 5; ++i){
    pd.src[i] = srcs[i]; pd.dst[i] = dsts[i]; pd.ET[i] = ets[i]; pd.K[i] = ks[i];
    pd.blkStart[i] = cum;
    cum += (ets[i] * 16 * ks[i] + 255) / 256;
  }
  pd.blkStart[5] = cum;
  pack_all_kernel<<<cum, 256, 0, stream>>>(pd);

  ln_kernel<<<4096, 256, 0, stream>>>(inp, lngi, lnbi, x);
  init_kernel<<<64, 256, 0, stream>>>(noise, mu, lsg, lngs, lnbs, wqkp, slots, qbuf);

  for(int it = 0; it < 3; ++it){
    attn_kernel<<<BB * NCH, 256, 0, stream>>>(x, qbuf, pupd, pms);
    update_kernel<<<64, 1024, 0, stream>>>(pupd, pms, slots, qbuf, mp, whhp,
        bih, bhh, w1p, b1, w2p, b2, lngs, lnbs, lngm, lnbm, wqkp, dout, (it == 2) ? 1 : 0);
  }
}